// Round 1
// baseline (817.897 us; speedup 1.0000x reference)
//
#include <hip/hip_runtime.h>
#include <math.h>

#define BB 64      // batch
#define NN 1152    // input capsules
#define DI 16      // dim input capsule
#define CC 32      // output capsules
#define DC 32      // dim output capsule
#define TN 16      // n-tile per block
#define TB 8       // batch-tile per block
#define CAPS_EPS 1e-7f

// One routing iteration, fused: recompute u_hat[c,n,:] on the fly,
// (T>0) update logits blog += dot(out_prev, u_hat), softmax over C,
// accumulate s[b,c,:] += coef * u_hat via atomics.
// Block: 256 threads; c = tid>>3 (32 capsules), jg = tid&7 (4 j's each).
// Grid: (NN/TN, BB/TB). W tile held in registers, reused across TB batches.
template<int T>
__global__ __launch_bounds__(256)
void route_k(const float* __restrict__ inp, const float* __restrict__ Wt,
             float* __restrict__ blog, float* __restrict__ sbuf,
             const float* __restrict__ outprev)
{
    const int tid  = threadIdx.x;
    const int c    = tid >> 3;
    const int jg   = tid & 7;
    const int j0   = jg * 4;
    const int lane = tid & 63;
    const int n0   = blockIdx.x * TN;
    const int b0   = blockIdx.y * TB;

    __shared__ float sh_in[TB][DI];
    __shared__ float sh_bl[CC];

    // previous-iteration outputs for this thread's (c, 4 j's), all TB batches
    float op[TB][4];
    if (T > 0) {
#pragma unroll
        for (int bb = 0; bb < TB; ++bb) {
            const float4 v = *(const float4*)(outprev + ((size_t)(b0 + bb) * CC + c) * DC + j0);
            op[bb][0] = v.x; op[bb][1] = v.y; op[bb][2] = v.z; op[bb][3] = v.w;
        }
    }

    float sp[TB][4];
#pragma unroll
    for (int bb = 0; bb < TB; ++bb) { sp[bb][0] = 0.f; sp[bb][1] = 0.f; sp[bb][2] = 0.f; sp[bb][3] = 0.f; }

    for (int nn = 0; nn < TN; ++nn) {
        const int n = n0 + nn;

        // W[c, n, j0..j0+3, 0..15] -> 64 registers (reused for all TB batches)
        float w[4][16];
        const float* wp = Wt + (((size_t)c * NN + n) * DC + j0) * DI;
#pragma unroll
        for (int jj = 0; jj < 4; ++jj) {
#pragma unroll
            for (int q = 0; q < 4; ++q) {
                const float4 v = ((const float4*)(wp + jj * DI))[q];
                w[jj][q * 4 + 0] = v.x; w[jj][q * 4 + 1] = v.y;
                w[jj][q * 4 + 2] = v.z; w[jj][q * 4 + 3] = v.w;
            }
        }

        __syncthreads();   // protect sh_in from previous n's readers
        if (tid < TB * 4) {
            const int bb = tid >> 2, q = tid & 3;
            ((float4*)(&sh_in[bb][0]))[q] =
                ((const float4*)(inp + ((size_t)(b0 + bb) * NN + n) * DI))[q];
        }
        __syncthreads();

#pragma unroll
        for (int bb = 0; bb < TB; ++bb) {
            // u_hat[b0+bb, c, n, j0+jj]
            float u0 = 0.f, u1 = 0.f, u2 = 0.f, u3 = 0.f;
#pragma unroll
            for (int i = 0; i < DI; ++i) {
                const float x = sh_in[bb][i];
                u0 = fmaf(w[0][i], x, u0);
                u1 = fmaf(w[1][i], x, u1);
                u2 = fmaf(w[2][i], x, u2);
                u3 = fmaf(w[3][i], x, u3);
            }

            float coef;
            if (T == 0) {
                coef = 1.0f / CC;   // softmax of zeros
            } else {
                // logit update: du = dot(out_prev[b,c,:], u_hat[b,c,n,:])
                float du = u0 * op[bb][0] + u1 * op[bb][1] + u2 * op[bb][2] + u3 * op[bb][3];
                du += __shfl_xor(du, 1);
                du += __shfl_xor(du, 2);
                du += __shfl_xor(du, 4);   // all 8 jg lanes now hold full dot

                const size_t bidx = ((size_t)(b0 + bb) * NN + n) * CC + c;
                const float bl = blog[bidx] + du;
                if (T == 1 && jg == 0) blog[bidx] = bl;   // persist for iteration 2
                if (jg == 0) sh_bl[c] = bl;
                __syncthreads();

                // softmax over the 32 capsules: lanes 0..31 of each wave mirror c'=0..31
                float mv = sh_bl[lane & 31];
#pragma unroll
                for (int m = 16; m >= 1; m >>= 1) mv = fmaxf(mv, __shfl_xor(mv, m));
                float ev = __expf(sh_bl[lane & 31] - mv);
#pragma unroll
                for (int m = 16; m >= 1; m >>= 1) ev += __shfl_xor(ev, m);
                coef = __expf(bl - mv) / ev;
                __syncthreads();   // sh_bl consumed before next bb overwrites
            }

            sp[bb][0] = fmaf(coef, u0, sp[bb][0]);
            sp[bb][1] = fmaf(coef, u1, sp[bb][1]);
            sp[bb][2] = fmaf(coef, u2, sp[bb][2]);
            sp[bb][3] = fmaf(coef, u3, sp[bb][3]);
        }
    }

#pragma unroll
    for (int bb = 0; bb < TB; ++bb) {
        float* so = sbuf + ((size_t)(b0 + bb) * CC + c) * DC + j0;
#pragma unroll
        for (int jj = 0; jj < 4; ++jj) atomicAdd(so + jj, sp[bb][jj]);
    }
}

// squash over Dc for each (b,c); one 32-lane group per capsule output.
// Also zero-fills sbuf for the next iteration's atomics (T<2).
template<int T>
__global__ __launch_bounds__(256)
void squash_k(float* __restrict__ sbuf, float* __restrict__ outp)
{
    const int tid = threadIdx.x;
    const int g   = tid >> 5;                 // 8 (b,c) groups per block
    const int j   = tid & 31;
    const int idx = blockIdx.x * 8 + g;       // flat (b*CC + c)
    const size_t base = (size_t)idx * DC;

    const float v = sbuf[base + j];
    float sq = v * v;
#pragma unroll
    for (int m = 16; m >= 1; m >>= 1) sq += __shfl_xor(sq, m);
    const float scale = sq / ((1.0f + sq) * sqrtf(sq + CAPS_EPS));
    outp[base + j] = scale * v;
    if (T < 2) sbuf[base + j] = 0.0f;
}

extern "C" void kernel_launch(void* const* d_in, const int* in_sizes, int n_in,
                              void* d_out, int out_size, void* d_ws, size_t ws_size,
                              hipStream_t stream)
{
    const float* inp = (const float*)d_in[0];   // [B, N, Di]
    const float* Wt  = (const float*)d_in[1];   // [C, N, Dc, Di]
    float* out  = (float*)d_out;                // [B, C, Dc]

    float* blog = (float*)d_ws;                          // [B, N, C] logits
    float* sbuf = blog + (size_t)BB * NN * CC;           // [B, C, Dc] weighted sums
    float* outb = sbuf + (size_t)BB * CC * DC;           // [B, C, Dc] prev outputs

    // workspace is poisoned 0xAA before every timed call: zero logits + s
    hipMemsetAsync(d_ws, 0,
                   ((size_t)BB * NN * CC + (size_t)BB * CC * DC) * sizeof(float),
                   stream);

    const dim3 gridA(NN / TN, BB / TB), blk(256);
    const dim3 gridS((BB * CC) / 8);

    route_k<0><<<gridA, blk, 0, stream>>>(inp, Wt, blog, sbuf, nullptr);
    squash_k<0><<<gridS, 256, 0, stream>>>(sbuf, outb);
    route_k<1><<<gridA, blk, 0, stream>>>(inp, Wt, blog, sbuf, outb);
    squash_k<1><<<gridS, 256, 0, stream>>>(sbuf, outb);
    route_k<2><<<gridA, blk, 0, stream>>>(inp, Wt, blog, sbuf, outb);
    squash_k<2><<<gridS, 256, 0, stream>>>(sbuf, out);
}

// Round 2
// 342.728 us; speedup vs baseline: 2.3864x; 2.3864x over previous
//
#include <hip/hip_runtime.h>
#include <math.h>

#define BB 64      // batch
#define NN 1152    // input capsules
#define DI 16      // dim input capsule
#define CC 32      // output capsules
#define DC 32      // dim output capsule
#define TN 16      // n-tile per route block
#define TB 4       // batch-tile per route block
#define NT (NN / TN)   // 72 n-tiles
#define CAPS_EPS 1e-7f

// workspace layout (floats)
#define WR_F   ((size_t)CC * NN * DC * DI)   // 18,874,368 transposed W
#define PART_F ((size_t)NT * BB * CC * DC)   // 4,718,592  per-ntile partial s
#define BLOG_F ((size_t)NN * BB * CC)        // 2,359,296  routing logits
#define OUTB_F ((size_t)BB * CC * DC)        // 65,536     prev outputs

// ---------------------------------------------------------------------------
// Transpose W[c][n][j][i] -> Wr[n][k][tid'] (float4 granularity) so that the
// route kernel's register fill is coalesced: chunk k=jj*4+q of thread
// tid'=c*8+jg holds W[c, n, jg*4+jj, q*4..q*4+3].
// Block: (ng, c) handles 16 n's of one c: reads 32 KB linearly, writes
// 128B-contiguous segments (full cache lines) via LDS.
// ---------------------------------------------------------------------------
__global__ __launch_bounds__(256)
void transpose_k(const float4* __restrict__ W4, float4* __restrict__ Wr4)
{
    const int tid = threadIdx.x;
    const int ng  = blockIdx.x;   // 72 groups of 16 n
    const int c   = blockIdx.y;   // 32
    __shared__ float4 sh[16 * 8 * 17];   // [nl][jg][17] (16 used, +1 pad)

    const size_t base = ((size_t)c * NN + (size_t)ng * 16) * (DC * DI / 4);
#pragma unroll
    for (int w = 0; w < 8; ++w) {
        const int l  = w * 256 + tid;        // 0..2047, coalesced read
        const int q  = l & 3;
        const int j  = (l >> 2) & 31;
        const int nl = l >> 7;
        const int jg = j >> 2;
        const int k  = (j & 3) * 4 + q;
        sh[(nl * 8 + jg) * 17 + k] = W4[base + l];
    }
    __syncthreads();
#pragma unroll
    for (int w = 0; w < 8; ++w) {
        const int s  = w * 32 + (tid >> 3);  // segment id: (nl,k)
        const int u  = tid & 7;              // jg within segment
        const int nl = s >> 4;
        const int k  = s & 15;
        const float4 v = sh[(nl * 8 + u) * 17 + k];
        const size_t o = ((size_t)((ng * 16 + nl) * 16 + k)) * 256 + c * 8 + u;
        Wr4[o] = v;   // 8-lane groups write 128B contiguous (full lines)
    }
}

// ---------------------------------------------------------------------------
// One routing iteration. Block: 256 threads = (c=tid>>3, jg=tid&7, j0=jg*4).
// Grid: (NT, BB/TB). Recomputes u_hat from Wr (coalesced) or W (fallback),
// batched softmax over C (3 barriers per n-step), writes per-ntile partial s.
// ---------------------------------------------------------------------------
template<int T, bool TR>
__global__ __launch_bounds__(256)
void route_k(const float* __restrict__ inp, const float* __restrict__ Wt,
             const float4* __restrict__ Wr4, float* __restrict__ blog,
             float4* __restrict__ part4, const float* __restrict__ outprev)
{
    const int tid = threadIdx.x;
    const int c   = tid >> 3;
    const int jg  = tid & 7;
    const int j0  = jg * 4;
    const int nt  = blockIdx.x;
    const int n0  = nt * TN;
    const int b0  = blockIdx.y * TB;

    __shared__ float sx[TB][TN][DI];   // inputs tile, staged once
    __shared__ float sh_bl[TB][CC];
    __shared__ float sh_cf[TB][CC];

    // stage inputs: 1 float4 per thread, coalesced per b-row
    {
        const int bb = tid >> 6, r = tid & 63, nn = r >> 2, q = r & 3;
        const float4 v = ((const float4*)inp)[((size_t)(b0 + bb) * NN + n0 + nn) * 4 + q];
        *(float4*)(&sx[bb][nn][q * 4]) = v;
    }

    float op0[TB], op1[TB], op2[TB], op3[TB];
    if (T > 0) {
#pragma unroll
        for (int bb = 0; bb < TB; ++bb) {
            const float4 v = *(const float4*)(outprev + ((size_t)(b0 + bb) * CC * DC) + tid * 4);
            op0[bb] = v.x; op1[bb] = v.y; op2[bb] = v.z; op3[bb] = v.w;
        }
    }

    float sp0[TB], sp1[TB], sp2[TB], sp3[TB];
#pragma unroll
    for (int bb = 0; bb < TB; ++bb) { sp0[bb] = 0.f; sp1[bb] = 0.f; sp2[bb] = 0.f; sp3[bb] = 0.f; }

    __syncthreads();

    for (int nn = 0; nn < TN; ++nn) {
        const int n = n0 + nn;

        // W fragment -> 64 registers
        float w[4][16];
        if (TR) {
            const size_t cb = (size_t)n * 16 * 256 + tid;
#pragma unroll
            for (int k = 0; k < 16; ++k) {
                const float4 v = Wr4[cb + (size_t)k * 256];
                w[k >> 2][(k & 3) * 4 + 0] = v.x; w[k >> 2][(k & 3) * 4 + 1] = v.y;
                w[k >> 2][(k & 3) * 4 + 2] = v.z; w[k >> 2][(k & 3) * 4 + 3] = v.w;
            }
        } else {
            const float* wp = Wt + (((size_t)c * NN + n) * DC + j0) * DI;
#pragma unroll
            for (int jj = 0; jj < 4; ++jj) {
#pragma unroll
                for (int q = 0; q < 4; ++q) {
                    const float4 v = ((const float4*)(wp + jj * DI))[q];
                    w[jj][q * 4 + 0] = v.x; w[jj][q * 4 + 1] = v.y;
                    w[jj][q * 4 + 2] = v.z; w[jj][q * 4 + 3] = v.w;
                }
            }
        }

        // u_hat for TB batches (sx reads are wave-uniform broadcasts)
        float u0[TB], u1[TB], u2[TB], u3[TB];
#pragma unroll
        for (int bb = 0; bb < TB; ++bb) {
            float a0 = 0.f, a1 = 0.f, a2 = 0.f, a3 = 0.f;
#pragma unroll
            for (int i = 0; i < DI; ++i) {
                const float x = sx[bb][nn][i];
                a0 = fmaf(w[0][i], x, a0);
                a1 = fmaf(w[1][i], x, a1);
                a2 = fmaf(w[2][i], x, a2);
                a3 = fmaf(w[3][i], x, a3);
            }
            u0[bb] = a0; u1[bb] = a1; u2[bb] = a2; u3[bb] = a3;
        }

        if (T == 0) {
#pragma unroll
            for (int bb = 0; bb < TB; ++bb) {
                sp0[bb] += u0[bb]; sp1[bb] += u1[bb];
                sp2[bb] += u2[bb]; sp3[bb] += u3[bb];
            }
        } else {
            // du[bb] = dot(out_prev, u_hat) reduced over jg (in-wave)
            float d0, d1, d2, d3;
            {
                float t0 = u0[0]*op0[0] + u1[0]*op1[0] + u2[0]*op2[0] + u3[0]*op3[0];
                float t1 = u0[1]*op0[1] + u1[1]*op1[1] + u2[1]*op2[1] + u3[1]*op3[1];
                float t2 = u0[2]*op0[2] + u1[2]*op1[2] + u2[2]*op2[2] + u3[2]*op3[2];
                float t3 = u0[3]*op0[3] + u1[3]*op1[3] + u2[3]*op2[3] + u3[3]*op3[3];
#pragma unroll
                for (int m = 1; m <= 4; m <<= 1) {
                    t0 += __shfl_xor(t0, m); t1 += __shfl_xor(t1, m);
                    t2 += __shfl_xor(t2, m); t3 += __shfl_xor(t3, m);
                }
                d0 = t0; d1 = t1; d2 = t2; d3 = t3;
            }
            if (jg < TB) {
                const float dsel = (jg == 0) ? d0 : (jg == 1) ? d1 : (jg == 2) ? d2 : d3;
                sh_bl[jg][c] = dsel;
            }
            __syncthreads();

            if (tid < TB * CC) {   // 128 softmax workers (waves 0,1)
                const int bb2 = tid >> 5, cc = tid & 31;
                float bl = sh_bl[bb2][cc];
                const size_t bix = ((size_t)n * BB + b0 + bb2) * CC + cc;
                if (T == 2) bl += blog[bix];
                if (T == 1) blog[bix] = bl;
                float mv = bl;
#pragma unroll
                for (int m = 1; m <= 16; m <<= 1) mv = fmaxf(mv, __shfl_xor(mv, m));
                float e = __expf(bl - mv), es = e;
#pragma unroll
                for (int m = 1; m <= 16; m <<= 1) es += __shfl_xor(es, m);
                sh_cf[bb2][cc] = e / es;
            }
            __syncthreads();

#pragma unroll
            for (int bb = 0; bb < TB; ++bb) {
                const float cf = sh_cf[bb][c];
                sp0[bb] = fmaf(cf, u0[bb], sp0[bb]);
                sp1[bb] = fmaf(cf, u1[bb], sp1[bb]);
                sp2[bb] = fmaf(cf, u2[bb], sp2[bb]);
                sp3[bb] = fmaf(cf, u3[bb], sp3[bb]);
            }
        }
    }

    // partial s, fully coalesced (4KB row per bb)
    const float sc = (T == 0) ? (1.0f / CC) : 1.0f;
#pragma unroll
    for (int bb = 0; bb < TB; ++bb) {
        float4 o;
        o.x = sp0[bb] * sc; o.y = sp1[bb] * sc; o.z = sp2[bb] * sc; o.w = sp3[bb] * sc;
        part4[((size_t)nt * BB + b0 + bb) * 256 + tid] = o;
    }
}

// ---------------------------------------------------------------------------
// Reduce 72 partials + squash. One block per b, 1024 threads (4 x 256).
// ---------------------------------------------------------------------------
__global__ __launch_bounds__(1024)
void reduce_k(const float4* __restrict__ part4, float4* __restrict__ dst)
{
    const int tid = threadIdx.x;
    const int t = tid & 255, g = tid >> 8;
    const int b = blockIdx.x;

    float4 a; a.x = 0.f; a.y = 0.f; a.z = 0.f; a.w = 0.f;
#pragma unroll
    for (int r = 0; r < NT / 4; ++r) {
        const int nt = g * (NT / 4) + r;
        const float4 v = part4[((size_t)nt * BB + b) * 256 + t];
        a.x += v.x; a.y += v.y; a.z += v.z; a.w += v.w;
    }
    __shared__ float4 sh[4][256];
    sh[g][t] = a;
    __syncthreads();
    if (g == 0) {
        const float4 v1 = sh[1][t], v2 = sh[2][t], v3 = sh[3][t];
        float4 s = a;
        s.x += v1.x + v2.x + v3.x; s.y += v1.y + v2.y + v3.y;
        s.z += v1.z + v2.z + v3.z; s.w += v1.w + v2.w + v3.w;
        float sq = s.x * s.x + s.y * s.y + s.z * s.z + s.w * s.w;
        sq += __shfl_xor(sq, 1); sq += __shfl_xor(sq, 2); sq += __shfl_xor(sq, 4);
        const float scale = sq / ((1.0f + sq) * sqrtf(sq + CAPS_EPS));
        float4 o; o.x = s.x * scale; o.y = s.y * scale; o.z = s.z * scale; o.w = s.w * scale;
        dst[(size_t)b * 256 + t] = o;
    }
}

extern "C" void kernel_launch(void* const* d_in, const int* in_sizes, int n_in,
                              void* d_out, int out_size, void* d_ws, size_t ws_size,
                              hipStream_t stream)
{
    const float* inp = (const float*)d_in[0];   // [B, N, Di]
    const float* Wt  = (const float*)d_in[1];   // [C, N, Dc, Di]
    float* out = (float*)d_out;                 // [B, C, Dc]

    const size_t needA = (WR_F + PART_F + BLOG_F + OUTB_F) * sizeof(float);
    const bool tr = (ws_size >= needA);

    float* base = (float*)d_ws;
    float* Wr   = tr ? base : nullptr;
    float* part = tr ? base + WR_F : base;
    float* blog = part + PART_F;
    float* outb = blog + BLOG_F;

    const dim3 gridR(NT, BB / TB), blk(256);
    float4* part4 = (float4*)part;
    const float4* Wr4 = (const float4*)Wr;

    if (tr) {
        transpose_k<<<dim3(72, 32), blk, 0, stream>>>((const float4*)Wt, (float4*)Wr);
        route_k<0, true><<<gridR, blk, 0, stream>>>(inp, Wt, Wr4, blog, part4, nullptr);
        reduce_k<<<BB, 1024, 0, stream>>>(part4, (float4*)outb);
        route_k<1, true><<<gridR, blk, 0, stream>>>(inp, Wt, Wr4, blog, part4, outb);
        reduce_k<<<BB, 1024, 0, stream>>>(part4, (float4*)outb);
        route_k<2, true><<<gridR, blk, 0, stream>>>(inp, Wt, Wr4, blog, part4, outb);
        reduce_k<<<BB, 1024, 0, stream>>>(part4, (float4*)out);
    } else {
        route_k<0, false><<<gridR, blk, 0, stream>>>(inp, Wt, Wr4, blog, part4, nullptr);
        reduce_k<<<BB, 1024, 0, stream>>>(part4, (float4*)outb);
        route_k<1, false><<<gridR, blk, 0, stream>>>(inp, Wt, Wr4, blog, part4, outb);
        reduce_k<<<BB, 1024, 0, stream>>>(part4, (float4*)outb);
        route_k<2, false><<<gridR, blk, 0, stream>>>(inp, Wt, Wr4, blog, part4, outb);
        reduce_k<<<BB, 1024, 0, stream>>>(part4, (float4*)out);
    }
}

// Round 7
// 217.250 us; speedup vs baseline: 3.7648x; 1.5776x over previous
//
#include <hip/hip_runtime.h>
#include <math.h>

using bh8    = __attribute__((ext_vector_type(8))) short;   // 8 x bf16
using f32x16 = __attribute__((ext_vector_type(16))) float;
typedef unsigned int u32;

#define NN   1152
#define CCAP 32
#define DI   16
#define DCAP 32
#define TNR  9          // n's per route block
#define NTILES 128      // 1152/9
#define CAPS_EPS 1e-7f

// LDS layout (bytes)
#define LDS_W    0        // 2 x 32KB W double-buffer: [buf][c][l][16B]
#define LDS_X    65536    // 9 KB x-frags: [n][l][16B]
#define LDS_DU   74752    // [32][33] f32
#define LDS_CF   78976    // [32][33] f32
#define LDS_TOT  83200

// workspace layout (bytes)
#define WS_WB    0ul          // 37,748,736  bf16 W frags [n][c][l][8]
#define WS_XB    37748736ul   //  2,359,296  bf16 x frags [h][n][l][8]
#define WS_PART  40108032ul   // 33,554,432  partial s [bk][c][l][16r] f32
#define WS_PART2 73662464ul   //  4,194,304  stage-2 partials
#define WS_OPK   77856768ul   //    131,072  out frags bf16 [h][c][plane][l][4w]
#define WS_BLOG  77987840ul   //  9,437,184  logits [n][c][h][b32]

__device__ __forceinline__ short f2bf(float f) {
    u32 u = __float_as_uint(f);
    u += 0x7fffu + ((u >> 16) & 1u);   // round-to-nearest-even
    return (short)(u >> 16);
}

__device__ __forceinline__ void gld_lds16(const void* g, void* s) {
    __builtin_amdgcn_global_load_lds(
        (const __attribute__((address_space(1))) u32*)g,
        (__attribute__((address_space(3))) u32*)s, 16, 0, 0);
}

// ---------------------------------------------------------------------------
// W[c][n][j][i] f32 -> Wb[n][c][l] bf16 A-frag chunks: lane l holds
// W[c, n, j=l&31, i = 8*(l>>5) .. +7].  Coalesced 16B writes.
// ---------------------------------------------------------------------------
__global__ __launch_bounds__(256)
void conv_w(const float* __restrict__ W, short* __restrict__ Wb)
{
    const int m = blockIdx.x * 256 + threadIdx.x;   // (n*32+c)*64+l
    const int l = m & 63, c = (m >> 6) & 31, n = m >> 11;
    const int j = l & 31, hi = l >> 5;
    const float* src = W + (((size_t)c * NN + n) * DCAP + j) * DI + hi * 8;
    const float4 a = ((const float4*)src)[0];
    const float4 b = ((const float4*)src)[1];
    bh8 r;
    r[0] = f2bf(a.x); r[1] = f2bf(a.y); r[2] = f2bf(a.z); r[3] = f2bf(a.w);
    r[4] = f2bf(b.x); r[5] = f2bf(b.y); r[6] = f2bf(b.z); r[7] = f2bf(b.w);
    *(bh8*)(Wb + (size_t)m * 8) = r;
}

// x[b][n][i] f32 -> xb[h][n][l] bf16 B-frag chunks: lane l holds
// x[b = h*32+(l&31), n, i = 8*(l>>5) .. +7].
__global__ __launch_bounds__(256)
void conv_x(const float* __restrict__ X, short* __restrict__ xb)
{
    const int m = blockIdx.x * 256 + threadIdx.x;   // (h*1152+n)*64+l
    const int l = m & 63;
    const int h = m / (NN * 64);
    const int n = (m >> 6) % NN;
    const int b = h * 32 + (l & 31), hi = l >> 5;
    const float* src = X + ((size_t)b * NN + n) * DI + hi * 8;
    const float4 a = ((const float4*)src)[0];
    const float4 c4 = ((const float4*)src)[1];
    bh8 r;
    r[0] = f2bf(a.x);  r[1] = f2bf(a.y);  r[2] = f2bf(a.z);  r[3] = f2bf(a.w);
    r[4] = f2bf(c4.x); r[5] = f2bf(c4.y); r[6] = f2bf(c4.z); r[7] = f2bf(c4.w);
    *(bh8*)(xb + (size_t)m * 8) = r;
}

// ---------------------------------------------------------------------------
// One routing iteration. Block: 512 thr = 8 waves x 4 c each; covers b-half h,
// all 32 c, TNR=9 n's. u_hatT[j,b] per (c,n) = one mfma_32x32x16_bf16.
// Prev-output frags are n-invariant -> held in 32 VGPRs (loaded once).
// ---------------------------------------------------------------------------
template<int T>
__global__ __launch_bounds__(512, 2)
void route_k(const short* __restrict__ Wb, const short* __restrict__ xb,
             const u32* __restrict__ opk, float* __restrict__ blog,
             float* __restrict__ part)
{
    extern __shared__ char smem[];
    const int tid = threadIdx.x;
    const int w = tid >> 6, l = tid & 63, bl31 = l & 31;
    const int nt = blockIdx.x, h = blockIdx.y;
    const int n0 = nt * TNR;
    const int bk = h * NTILES + nt;

    char* Wl  = smem + LDS_W;
    char* Xl  = smem + LDS_X;
    float* DU = (float*)(smem + LDS_DU);
    float* CF = (float*)(smem + LDS_CF);

    // ---- prologue staging ----
    {
        const char* xs = (const char*)(xb + ((size_t)h * NN + n0) * 512);
        gld_lds16(xs + tid * 16, Xl + tid * 16);
        if (tid < 64) gld_lds16(xs + (512 + tid) * 16, Xl + (512 + tid) * 16);
    }
    {
        const char* wsrc = (const char*)(Wb + (size_t)n0 * 16384);
#pragma unroll
        for (int k = 0; k < 4; ++k)
            gld_lds16(wsrc + (k * 512 + tid) * 16, Wl + (k * 512 + tid) * 16);
    }

    // prev-output bf16 frags -> registers (n-invariant): out[b=bl31, c, 16 j's of hi-half]
    uint4 opr[4][2];
    if (T > 0) {
#pragma unroll
        for (int cc = 0; cc < 4; ++cc) {
            const int c = w * 4 + cc;
            const char* ob = (const char*)opk;
            opr[cc][0] = *(const uint4*)(ob + ((((size_t)h * CCAP + c) * 2 + 0) * 64 + l) * 16);
            opr[cc][1] = *(const uint4*)(ob + ((((size_t)h * CCAP + c) * 2 + 1) * 64 + l) * 16);
        }
    }
    __syncthreads();

    f32x16 sacc[4];
#pragma unroll
    for (int cc = 0; cc < 4; ++cc)
#pragma unroll
        for (int r = 0; r < 16; ++r) sacc[cc][r] = 0.f;

    for (int n = 0; n < TNR; ++n) {
        const int buf = n & 1;
        const int na = n0 + n;

        // prefetch next W tile into the other buffer
        if (n + 1 < TNR) {
            const char* wsrc = (const char*)(Wb + (size_t)(na + 1) * 16384);
            char* wdst = Wl + (buf ^ 1) * 32768;
#pragma unroll
            for (int k = 0; k < 4; ++k)
                gld_lds16(wsrc + (k * 512 + tid) * 16, wdst + (k * 512 + tid) * 16);
        }

        const bh8 xf = *(const bh8*)(Xl + n * 1024 + l * 16);
        bh8 wf[4];
#pragma unroll
        for (int cc = 0; cc < 4; ++cc) {
            const int c = w * 4 + cc;
            wf[cc] = *(const bh8*)(Wl + buf * 32768 + (c * 64 + l) * 16);
        }

        if (T == 0) {
            // coef uniform: s = (1/32) sum_n u_hat — accumulate directly in MFMA
#pragma unroll
            for (int cc = 0; cc < 4; ++cc)
                sacc[cc] = __builtin_amdgcn_mfma_f32_32x32x16_bf16(wf[cc], xf, sacc[cc], 0, 0, 0);
        } else {
            f32x16 zz;
#pragma unroll
            for (int r = 0; r < 16; ++r) zz[r] = 0.f;
            f32x16 u[4];
#pragma unroll
            for (int cc = 0; cc < 4; ++cc)
                u[cc] = __builtin_amdgcn_mfma_f32_32x32x16_bf16(wf[cc], xf, zz, 0, 0, 0);

            // du[b] = sum_j out[b,c,j] * u_hatT[j,b]  — lane-local over 16 j's
            float du[4];
#pragma unroll
            for (int cc = 0; cc < 4; ++cc) {
                const u32 o[8] = {opr[cc][0].x, opr[cc][0].y, opr[cc][0].z, opr[cc][0].w,
                                  opr[cc][1].x, opr[cc][1].y, opr[cc][1].z, opr[cc][1].w};
                float d = 0.f;
#pragma unroll
                for (int p = 0; p < 8; ++p) {
                    const float e0 = __uint_as_float(o[p] << 16);
                    const float e1 = __uint_as_float(o[p] & 0xffff0000u);
                    d = fmaf(e0, u[cc][2 * p + 0], d);
                    d = fmaf(e1, u[cc][2 * p + 1], d);
                }
                d += __shfl_xor(d, 32);           // add partner j-half
                const int c = w * 4 + cc;
                if (T == 2) d += blog[(((size_t)na * CCAP + c) * 2 + h) * 32 + bl31];
                du[cc] = d;
            }
#pragma unroll
            for (int cc = 0; cc < 4; ++cc) {
                const int c = w * 4 + cc;
                if (l < 32) {
                    DU[c * 33 + l] = du[cc];
                    if (T == 1) blog[(((size_t)na * CCAP + c) * 2 + h) * 32 + l] = du[cc];
                }
            }
            __syncthreads();

            // softmax over c for each b: t -> (b = t>>4, g = t&15), 2 c's each
            {
                const int b = tid >> 4, g = tid & 15;
                const float v0 = DU[g * 33 + b], v1 = DU[(g + 16) * 33 + b];
                float m = fmaxf(v0, v1);
#pragma unroll
                for (int d2 = 1; d2 < 16; d2 <<= 1) m = fmaxf(m, __shfl_xor(m, d2));
                const float e0 = __expf(v0 - m), e1 = __expf(v1 - m);
                float es = e0 + e1;
#pragma unroll
                for (int d2 = 1; d2 < 16; d2 <<= 1) es += __shfl_xor(es, d2);
                const float inv = 1.0f / es;
                CF[g * 33 + b] = e0 * inv;
                CF[(g + 16) * 33 + b] = e1 * inv;
            }
            __syncthreads();

#pragma unroll
            for (int cc = 0; cc < 4; ++cc) {
                const int c = w * 4 + cc;
                const float cf = CF[c * 33 + bl31];
#pragma unroll
                for (int r = 0; r < 16; ++r)
                    sacc[cc][r] = fmaf(cf, u[cc][r], sacc[cc][r]);
            }
        }
        if (T == 0) __syncthreads();   // T>0: interior barriers already order buf reuse
    }

    // write partial s in frag layout [bk][c][l][16r], coalesced dwordx4
#pragma unroll
    for (int cc = 0; cc < 4; ++cc) {
        const int c = w * 4 + cc;
        float* dst = part + (((size_t)bk * CCAP + c) * 64 + l) * 16;
#pragma unroll
        for (int k = 0; k < 4; ++k) {
            float4 v;
            v.x = sacc[cc][4 * k + 0]; v.y = sacc[cc][4 * k + 1];
            v.z = sacc[cc][4 * k + 2]; v.w = sacc[cc][4 * k + 3];
            ((float4*)dst)[k] = v;
        }
    }
}

// ---------------------------------------------------------------------------
// Stage-1 reduce: sum 8 n-tiles per block. grid (ch=16, c=32, h=2).
// ---------------------------------------------------------------------------
__global__ __launch_bounds__(1024)
void reduce1_k(const float* __restrict__ part, float* __restrict__ part2)
{
    const int t = threadIdx.x;
    const int ch = blockIdx.x, c = blockIdx.y, h = blockIdx.z;
    float a = 0.f;
#pragma unroll
    for (int s = 0; s < 8; ++s) {
        const int nt = ch * 8 + s;
        a += part[((size_t)(h * NTILES + nt) * CCAP + c) * 1024 + t];
    }
    part2[(((size_t)h * CCAP + c) * 16 + ch) * 1024 + t] = a;
}

// ---------------------------------------------------------------------------
// Stage-2: final sum + squash. grid (c=32, h=2). t -> (l = t>>4, r = t&15).
// FIN=0: writes bf16 out-frags (for next route's du). FIN=1: writes d_out.
// ---------------------------------------------------------------------------
template<int FIN>
__global__ __launch_bounds__(1024)
void reduce2_k(const float* __restrict__ part2, u32* __restrict__ opk,
               float* __restrict__ outp, float sc0)
{
    const int t = threadIdx.x;
    const int c = blockIdx.x, h = blockIdx.y;
    const int l = t >> 4, r = t & 15;
    float s = 0.f;
#pragma unroll
    for (int ch = 0; ch < 16; ++ch)
        s += part2[(((size_t)h * CCAP + c) * 16 + ch) * 1024 + t];
    s *= sc0;

    float q = s * s;
    q += __shfl_xor(q, 1); q += __shfl_xor(q, 2);
    q += __shfl_xor(q, 4); q += __shfl_xor(q, 8);
    __shared__ float ssq[64], scl[32];
    if (r == 0) ssq[l] = q;
    __syncthreads();
    if (t < 32) {
        const float v = ssq[t] + ssq[t + 32];
        scl[t] = v / ((1.0f + v) * sqrtf(v + CAPS_EPS));
    }
    __syncthreads();
    const float o = s * scl[l & 31];

    if (FIN) {
        const int b = h * 32 + (l & 31);
        const int j = (r & 3) + 8 * (r >> 2) + 4 * (l >> 5);
        outp[((size_t)b * CCAP + c) * DCAP + j] = o;
    } else {
        const float o1 = __shfl_xor(o, 1);
        if (!(r & 1)) {
            const u32 pk = (u32)(unsigned short)f2bf(o) |
                           ((u32)(unsigned short)f2bf(o1) << 16);
            opk[((((size_t)h * CCAP + c) * 2 + (r >> 3)) * 64 + l) * 4 + ((r >> 1) & 3)] = pk;
        }
    }
}

extern "C" void kernel_launch(void* const* d_in, const int* in_sizes, int n_in,
                              void* d_out, int out_size, void* d_ws, size_t ws_size,
                              hipStream_t stream)
{
    const float* inp = (const float*)d_in[0];   // [B, N, Di]
    const float* Wt  = (const float*)d_in[1];   // [C, N, Dc, Di]
    float* out = (float*)d_out;                 // [B, C, Dc]

    char* ws = (char*)d_ws;
    short* Wb    = (short*)(ws + WS_WB);
    short* xb    = (short*)(ws + WS_XB);
    float* part  = (float*)(ws + WS_PART);
    float* part2 = (float*)(ws + WS_PART2);
    u32*   opk   = (u32*)  (ws + WS_OPK);
    float* blog  = (float*)(ws + WS_BLOG);

    hipFuncSetAttribute((const void*)route_k<0>, hipFuncAttributeMaxDynamicSharedMemorySize, LDS_TOT);
    hipFuncSetAttribute((const void*)route_k<1>, hipFuncAttributeMaxDynamicSharedMemorySize, LDS_TOT);
    hipFuncSetAttribute((const void*)route_k<2>, hipFuncAttributeMaxDynamicSharedMemorySize, LDS_TOT);

    conv_w<<<9216, 256, 0, stream>>>(Wt, Wb);
    conv_x<<<576, 256, 0, stream>>>(inp, xb);

    const dim3 gr(NTILES, 2), br(512);
    const dim3 g1(16, 32, 2);
    const dim3 g2(32, 2);

    route_k<0><<<gr, br, LDS_TOT, stream>>>(Wb, xb, opk, blog, part);
    reduce1_k<<<g1, 1024, 0, stream>>>(part, part2);
    reduce2_k<0><<<g2, 1024, 0, stream>>>(part2, opk, out, 1.0f / 32.0f);

    route_k<1><<<gr, br, LDS_TOT, stream>>>(Wb, xb, opk, blog, part);
    reduce1_k<<<g1, 1024, 0, stream>>>(part, part2);
    reduce2_k<0><<<g2, 1024, 0, stream>>>(part2, opk, out, 1.0f);

    route_k<2><<<gr, br, LDS_TOT, stream>>>(Wb, xb, opk, blog, part);
    reduce1_k<<<g1, 1024, 0, stream>>>(part, part2);
    reduce2_k<1><<<g2, 1024, 0, stream>>>(part2, opk, out, 1.0f);
}